// Round 10
// baseline (2974.894 us; speedup 1.0000x reference)
//
#include <hip/hip_runtime.h>
#include <stdint.h>

#define BB 8
#define NN 16384
#define SS 1024

typedef unsigned short u16;
typedef float f32x4 __attribute__((ext_vector_type(4)));
typedef short short8v __attribute__((ext_vector_type(8)));
typedef unsigned short us4 __attribute__((ext_vector_type(4)));
typedef unsigned short us8 __attribute__((ext_vector_type(8)));

static __device__ __forceinline__ float bf2f(u16 u){
    union { uint32_t u; float f; } v; v.u = ((uint32_t)u) << 16; return v.f;
}
static __device__ __forceinline__ u16 f2bf(float f){
    union { float f; uint32_t u; } v; v.f = f;
    return (u16)((v.u + 0x7FFFu + ((v.u >> 16) & 1u)) >> 16);
}
static constexpr int cmax2(int a, int b){ return a > b ? a : b; }

// ======== FAT pre-kernel: FPS (blocks 0..7) + ptsT transpose (8..2055) + W convert ====
// FPS history: ~1770us with 64 persistent array floats -> gfx950 unified-RF allocator
// parks them in AGPRs, ~200 ops/wave/iter of accvgpr move tax (R5/R6/R7: occupancy
// attrs + asm constraints can't change placement). R10: shrink persistent state to
// 28 floats (4 reg-pts for [LP,NN) + dd[16]); coords for [0,LP) are re-read from the
// LDS cache each iter (36 ds_read_b32/thread, offset-immediate, 2-way alias = free,
// LDS BW 576cy/iter << VALU 1840cy). Bit-exact: verbatim f32 copies, same op order.
#define LP 12288
#define SM_FPS (LP*3*4 + SS*4 + 8)

__global__ __launch_bounds__(1024) void pre_kernel(
        const float* __restrict__ xyz, const float* __restrict__ pts,
        float* __restrict__ ptsT, float* __restrict__ q, float* __restrict__ out_xyz,
        const float* __restrict__ w0, const float* __restrict__ w1, const float* __restrict__ w2,
        const float* __restrict__ w3, const float* __restrict__ w4, const float* __restrict__ w5,
        const float* __restrict__ w6, const float* __restrict__ w7, const float* __restrict__ w8,
        u16* __restrict__ wbf0, u16* __restrict__ wbf1, u16* __restrict__ wbf2){
#pragma clang fp contract(off)
    __shared__ __align__(16) char smem_raw[SM_FPS];
    int t = threadIdx.x;

    if (blockIdx.x >= 8){
        int bx = blockIdx.x - 8;
        if (bx < 2048){
            float (*tile)[65] = (float (*)[65])smem_raw;
            int b = bx >> 8;
            int n0 = (bx & 255) * 64;
            int ln = t & 63, cr = t >> 6;
            for (int c = cr; c < 64; c += 16){
                float v;
                if (c < 3) v = xyz[((size_t)b*3 + c)*NN + n0 + ln];
                else       v = pts[((size_t)b*61 + (c-3))*NN + n0 + ln];
                tile[ln][c] = v;
            }
            __syncthreads();
            int lc = t & 63, nr = t >> 6;
            for (int n = nr; n < 64; n += 16){
                ptsT[((size_t)b*NN + n0 + n)*64 + lc] = tile[n][lc];
            }
        } else {
            int br = bx - 2048;
            const float* A; const float* B; const float* C; u16* out; int na, nb2, nc;
            if (br == 0){ A=w0; na=4096;  B=w1; nb2=4096;  C=w2; nc=8192;  out=wbf0; }
            else if (br == 1){ A=w3; na=8192; B=w4; nb2=16384; C=w5; nc=32768; out=wbf1; }
            else { A=w6; na=8192; B=w7; nb2=16384; C=w8; nc=32768; out=wbf2; }
            int tot = na + nb2 + nc;
            for (int i = t; i < tot; i += 1024){
                float v;
                if (i < na) v = A[i];
                else if (i < na+nb2) v = B[i-na];
                else v = C[i-na-nb2];
                out[i] = f2bf(v);
            }
        }
        return;
    }

    // ---- FPS branch ----
    float* lx = (float*)smem_raw;
    float* ly = lx + LP;
    float* lz = ly + LP;
    int*  hist = (int*)(lz + LP);
    unsigned long long* slotp = (unsigned long long*)(hist + SS);
    int b = blockIdx.x;
    const float* xb = xyz + (size_t)b*3*NN;
    // persistent register state: 4 reg-points (12 floats) + dd[16] = 28 floats
    float px[4], py[4], pz[4], dd[16];
#pragma unroll
    for (int j=0;j<4;++j){
        int n = t + (12+j)*1024;
        px[j] = xb[n];
        py[j] = xb[NN+n];
        pz[j] = xb[2*NN+n];
    }
#pragma unroll
    for (int j=0;j<16;++j) dd[j] = 1e10f;
    // opaque redefinition: compiler cannot rematerialize the 12 reg-coord loads
#pragma unroll
    for (int j=0;j<4;++j){
        asm volatile("" : "+v"(px[j]), "+v"(py[j]), "+v"(pz[j]));
    }
    for (int idx = t; idx < LP; idx += 1024){
        lx[idx] = xb[idx];
        ly[idx] = xb[NN+idx];
        lz[idx] = xb[2*NN+idx];
    }
    if (t == 0) *slotp = 0ull;
    __syncthreads();

    int lane = t & 63;
    int far = 0;
    float cx = xb[0], cy = xb[NN], cz = xb[2*NN];
    for (int it=0; it<SS; ++it){
        if (t==0) hist[it] = far;
        // pts [0,LP): coords from LDS cache (base + offset-imm ds_read_b32)
#pragma unroll
        for (int j=0;j<12;++j){
            float x = lx[t + j*1024];
            float y = ly[t + j*1024];
            float z = lz[t + j*1024];
            float dx = x-cx, dy = y-cy, dz = z-cz;
            float d = dx*dx + dy*dy;
            d = d + dz*dz;
            dd[j] = fminf(dd[j], d);   // np.minimum, exact
        }
        // pts [LP,NN): register-resident coords
#pragma unroll
        for (int j=0;j<4;++j){
            float dx = px[j]-cx, dy = py[j]-cy, dz = pz[j]-cz;
            float d = dx*dx + dy*dy;
            d = d + dz*dz;
            dd[12+j] = fminf(dd[12+j], d);
        }
        float m01 = fmaxf(dd[0], dd[1]),  m23 = fmaxf(dd[2], dd[3]);
        float m45 = fmaxf(dd[4], dd[5]),  m67 = fmaxf(dd[6], dd[7]);
        float m89 = fmaxf(dd[8], dd[9]),  mab = fmaxf(dd[10], dd[11]);
        float mcd = fmaxf(dd[12], dd[13]), mef = fmaxf(dd[14], dd[15]);
        float ma = fmaxf(fmaxf(m01, m23), fmaxf(m45, m67));
        float mb = fmaxf(fmaxf(m89, mab), fmaxf(mcd, mef));
        float mx = fmaxf(ma, mb);
        int bj = 0;
#pragma unroll
        for (int j=15; j>=0; --j){
            if (dd[j] == mx) bj = j;
        }
        int bn = t + (bj << 10);
        unsigned long long pk = ((unsigned long long)(unsigned)(it+1) << 46)
                              | ((unsigned long long)__float_as_uint(mx) << 14)
                              | (unsigned long long)(unsigned)(16383 - bn);
#pragma unroll
        for (int off=32; off>0; off>>=1){
            unsigned long long o = __shfl_down(pk, off);
            pk = (o > pk) ? o : pk;
        }
        if (lane == 0) atomicMax(slotp, pk);
        __syncthreads();
        unsigned long long win = *slotp;
        far = 16383 - (int)(win & 0x3FFFull);
        if (far < LP){
            cx = lx[far]; cy = ly[far]; cz = lz[far];
        } else {
            cx = xb[far]; cy = xb[NN+far]; cz = xb[2*NN+far];
        }
    }
    __syncthreads();
    {
        int s = t;
        int fidx = hist[s];
        float vx, vy, vz;
        if (fidx < LP){ vx = lx[fidx]; vy = ly[fidx]; vz = lz[fidx]; }
        else { vx = xb[fidx]; vy = xb[NN+fidx]; vz = xb[2*NN+fidx]; }
        int gi = b*SS + s;
        q[gi*3+0] = vx; q[gi*3+1] = vy; q[gi*3+2] = vz;
        out_xyz[((size_t)b*3+0)*SS + s] = vx;
        out_xyz[((size_t)b*3+1)*SS + s] = vy;
        out_xyz[((size_t)b*3+2)*SS + s] = vz;
    }
}

// ---------------- ball query ----------------
__global__ __launch_bounds__(256) void ballquery_kernel(const float* __restrict__ xyz, const float* __restrict__ q,
        int* __restrict__ idx0, int* __restrict__ idx1, int* __restrict__ idx2,
        float r2a, float r2b, float r2c){
#pragma clang fp contract(off)
    __shared__ int lds[4][112];
    int t = threadIdx.x;
    int w = t >> 6, lane = t & 63;
    int qi = blockIdx.x*4 + w;
    int b = qi >> 10;
    const float* xb = xyz + (size_t)b*3*NN;
    float qx = q[qi*3], qy = q[qi*3+1], qz = q[qi*3+2];
    float qn = qx*qx + qy*qy; qn = qn + qz*qz;
    int* l0 = lds[w];
    int* l1 = l0 + 16;
    int* l2 = l0 + 48;
    l0[lane] = 0;
    if (lane < 48) l0[64+lane] = 0;
    int c0=0, c1=0, c2=0;
    uint64_t below = (1ull << lane) - 1ull;
    for (int ch=0; ch<256; ++ch){
        int n = ch*64 + lane;
        float x = xb[n], y = xb[NN+n], z = xb[2*NN+n];
        float dn = x*x + y*y; dn = dn + z*z;
        float dot = qx*x + qy*y; dot = dot + qz*z;
        float d = -2.0f*dot + qn;
        d = d + dn;
        bool o0 = d <= r2a, o1 = d <= r2b, o2 = d <= r2c;
        uint64_t m0 = __ballot(o0), m1 = __ballot(o1), m2 = __ballot(o2);
        if (c0 < 16){
            int p = c0 + (int)__popcll(m0 & below);
            if (o0 && p < 16) l0[p] = n;
            c0 += (int)__popcll(m0); if (c0 > 16) c0 = 16;
        }
        if (c1 < 32){
            int p = c1 + (int)__popcll(m1 & below);
            if (o1 && p < 32) l1[p] = n;
            c1 += (int)__popcll(m1); if (c1 > 32) c1 = 32;
        }
        if (c2 < 64){
            int p = c2 + (int)__popcll(m2 & below);
            if (o2 && p < 64) l2[p] = n;
            c2 += (int)__popcll(m2); if (c2 > 64) c2 = 64;
        }
        if (c0>=16 && c1>=32 && c2>=64) break;
    }
    __syncthreads();
    int f0 = l0[0], f1 = l1[0], f2 = l2[0];
    if (lane >= c0 && lane < 16) l0[lane] = f0;
    if (lane >= c1 && lane < 32) l1[lane] = f1;
    if (lane >= c2)              l2[lane] = f2;
    __syncthreads();
    if (lane < 16) idx0[(size_t)qi*16 + lane] = l0[lane];
    if (lane < 32) idx1[(size_t)qi*32 + lane] = l1[lane];
    idx2[(size_t)qi*64 + lane] = l2[lane];
}

// =================== MFMA fused MLP primitives ===================
template<int CC, int OH>
__device__ __forceinline__ void load_W_frags(const u16* __restrict__ Wb,
                                             short8v (&wf)[CC/32][OH/64],
                                             int l, int w, int hoff){
    int rl = l & 15, kg = l >> 4;
#pragma unroll
    for (int ks=0; ks<CC/32; ++ks)
#pragma unroll
    for (int tc=0; tc<OH/64; ++tc){
        int col = hoff + w*(OH/4) + tc*16 + rl;
        wf[ks][tc] = *(const short8v*)(Wb + (size_t)col*CC + ks*32 + kg*8);
    }
}

template<int K>
__device__ __forceinline__ void stage_A_gather(const float* __restrict__ ptsT, const float* __restrict__ q,
                                               const int* __restrict__ gidx, int m0, int t, char* __restrict__ As){
    int r = t >> 2, q4 = t & 3;
    int m = m0 + r;
    int idx = gidx[m];
    int bs = m / K;
    int b = bs >> 10;
    const float* base = ptsT + ((size_t)b*NN + idx)*64;
    float qx=0.f, qy=0.f, qz=0.f;
    if (q4 == 0){ qx = q[bs*3]; qy = q[bs*3+1]; qz = q[bs*3+2]; }
    int rx = (r & 7) << 4;
#pragma unroll
    for (int ii=0; ii<4; ++ii){
        int c0 = q4*16 + ii*4;
        float4 v = *(const float4*)(base + c0);
        if (q4==0 && ii==0){ v.x -= qx; v.y -= qy; v.z -= qz; }
        us4 u;
        u[0]=f2bf(v.x); u[1]=f2bf(v.y); u[2]=f2bf(v.z); u[3]=f2bf(v.w);
        *(us4*)(As + r*128 + ((c0*2) ^ rx)) = u;
    }
}

template<int OP>
__device__ __forceinline__ void stage_A_z(const u16* __restrict__ zbuf, int m0,
                                          const float* __restrict__ sc, const float* __restrict__ sh,
                                          int t, char* __restrict__ As){
    constexpr int CQ = OP/4;
    for (int s = t; s < 64*CQ; s += 256){
        int r = s / CQ, cq = s - r*CQ;
        us4 zv = *(const us4*)&zbuf[((size_t)(m0+r))*OP + cq*4];
        int c = cq*4;
        us4 u;
        u[0] = f2bf(fmaxf(0.f, bf2f(zv[0])*sc[c+0] + sh[c+0]));
        u[1] = f2bf(fmaxf(0.f, bf2f(zv[1])*sc[c+1] + sh[c+1]));
        u[2] = f2bf(fmaxf(0.f, bf2f(zv[2])*sc[c+2] + sh[c+2]));
        u[3] = f2bf(fmaxf(0.f, bf2f(zv[3])*sc[c+3] + sh[c+3]));
        *(us4*)(As + r*(OP*2) + ((cq*8) ^ ((r&7)<<4))) = u;
    }
}

template<int CC, int OH>
__device__ __forceinline__ void mfma_gemm_v2(const char* __restrict__ As,
                                             const short8v (&wf)[CC/32][OH/64],
                                             f32x4 (&acc)[4][OH/64], int l){
    constexpr int CCB = CC*2;
    int rl = l & 15, kg = l >> 4;
    const char* ap = As + rl*CCB;
    int axor = (rl & 7) << 4;
#pragma unroll
    for (int ks=0; ks<CC/32; ++ks){
        int karg = ((ks<<6) | (kg<<4)) ^ axor;
        short8v a0 = *(const short8v*)(ap + 0*16*CCB + karg);
        short8v a1 = *(const short8v*)(ap + 1*16*CCB + karg);
        short8v a2 = *(const short8v*)(ap + 2*16*CCB + karg);
        short8v a3 = *(const short8v*)(ap + 3*16*CCB + karg);
#pragma unroll
        for (int tc=0; tc<OH/64; ++tc){
            acc[0][tc] = __builtin_amdgcn_mfma_f32_16x16x32_bf16(a0, wf[ks][tc], acc[0][tc], 0,0,0);
            acc[1][tc] = __builtin_amdgcn_mfma_f32_16x16x32_bf16(a1, wf[ks][tc], acc[1][tc], 0,0,0);
            acc[2][tc] = __builtin_amdgcn_mfma_f32_16x16x32_bf16(a2, wf[ks][tc], acc[2][tc], 0,0,0);
            acc[3][tc] = __builtin_amdgcn_mfma_f32_16x16x32_bf16(a3, wf[ks][tc], acc[3][tc], 0,0,0);
        }
    }
}

template<int OH>
__device__ __forceinline__ void bias_mfma(f32x4 (&acc)[4][OH/64], const float* __restrict__ bsrc,
                                          int l, int w, int coff){
#pragma unroll
    for (int tc=0; tc<OH/64; ++tc){
        float bb = bsrc[coff + w*(OH/4) + tc*16 + (l&15)];
#pragma unroll
        for (int tr=0; tr<4; ++tr)
#pragma unroll
        for (int e=0; e<4; ++e) acc[tr][tc][e] += bb;
    }
}

template<int OH, int OT>
__device__ __forceinline__ void zstore_mfma(f32x4 (&acc)[4][OH/64], u16* __restrict__ zbuf,
                                            int m0, int l, int w, int coff){
#pragma unroll
    for (int tr=0; tr<4; ++tr)
#pragma unroll
    for (int e=0; e<4; ++e){
        int row = tr*16 + (l>>4)*4 + e;
#pragma unroll
        for (int tc=0; tc<OH/64; ++tc){
            int c = coff + w*(OH/4) + tc*16 + (l&15);
            zbuf[((size_t)(m0+row))*OT + c] = f2bf(acc[tr][tc][e]);
        }
    }
}

template<int OH, int OT, int K, bool EXT>
__device__ __forceinline__ void stats_mfma(f32x4 (&acc)[4][OH/64], int l, int w, int m0, int blk, int coff,
    float* __restrict__ pS, float* __restrict__ pQ,
    float* __restrict__ gmax, float* __restrict__ gmin){
#pragma unroll
    for (int tc=0; tc<OH/64; ++tc){
        float s1 = 0.f, s2 = 0.f;
        float mxr[4], mnr[4];
#pragma unroll
        for (int tr=0; tr<4; ++tr){
            float v0=acc[tr][tc][0], v1=acc[tr][tc][1], v2=acc[tr][tc][2], v3=acc[tr][tc][3];
            s1 += (v0+v1)+(v2+v3);
            s2 += (v0*v0+v1*v1)+(v2*v2+v3*v3);
            if (EXT){
                mxr[tr] = fmaxf(fmaxf(v0,v1),fmaxf(v2,v3));
                mnr[tr] = fminf(fminf(v0,v1),fminf(v2,v3));
            }
        }
        s1 += __shfl_xor(s1,16); s1 += __shfl_xor(s1,32);
        s2 += __shfl_xor(s2,16); s2 += __shfl_xor(s2,32);
        if (EXT){
#pragma unroll
            for (int tr=0; tr<4; ++tr){
                mxr[tr] = fmaxf(mxr[tr], __shfl_xor(mxr[tr],16));
                mxr[tr] = fmaxf(mxr[tr], __shfl_xor(mxr[tr],32));
                mnr[tr] = fminf(mnr[tr], __shfl_xor(mnr[tr],16));
                mnr[tr] = fminf(mnr[tr], __shfl_xor(mnr[tr],32));
            }
        }
        if (l < 16){
            int c = coff + w*(OH/4) + tc*16 + l;
            pS[(size_t)blk*OT + c] = s1;
            pQ[(size_t)blk*OT + c] = s2;
            if (EXT){
                constexpr int G = 64/K, WG = K/16;
#pragma unroll
                for (int g=0; g<G; ++g){
                    float M1 = mxr[g*WG], M2 = mnr[g*WG];
#pragma unroll
                    for (int ww=1; ww<WG; ++ww){
                        M1 = fmaxf(M1, mxr[g*WG+ww]);
                        M2 = fminf(M2, mnr[g*WG+ww]);
                    }
                    gmax[(size_t)(m0/K + g)*OT + c] = M1;
                    gmin[(size_t)(m0/K + g)*OT + c] = M2;
                }
            }
        }
    }
}

template<int OH>
__device__ __forceinline__ void act_to_As_mfma(f32x4 (&acc)[4][OH/64], const float* __restrict__ bsrc,
    const float* __restrict__ sc, const float* __restrict__ sh, int l, int w, char* __restrict__ As){
#pragma unroll
    for (int tc=0; tc<OH/64; ++tc){
        int c = w*(OH/4) + tc*16 + (l&15);
        float bb = bsrc[c], scv = sc[c], shv = sh[c];
#pragma unroll
        for (int tr=0; tr<4; ++tr)
#pragma unroll
        for (int e=0; e<4; ++e){
            int row = tr*16 + (l>>4)*4 + e;
            float vv = fmaxf(0.f, (acc[tr][tc][e]+bb)*scv + shv);
            *(u16*)(As + row*(OH*2) + ((2*c) ^ ((row&7)<<4))) = f2bf(vv);
        }
    }
}

// =================== MERGED path: one launch per stage, branches concurrent ========
struct BrP {
    const int* gidx;
    const u16 *W1, *W2, *W3;
    const float *b1, *b2, *b3;
    const float *sc1, *sh1, *sc2, *sh2;
    float *pS, *pQ, *gmax, *gmin;
    u16* zbuf;
};

template<int PHASE, int K, int O1, int O2, int O3>
__device__ __forceinline__ void mlp_phase(const float* __restrict__ ptsT, const float* __restrict__ q,
                                          const BrP& P, int blk, int t, char* As){
    constexpr int OH3 = (O3 > 128) ? 128 : O3;
    int l = t & 63, w = t >> 6;
    int m0 = blk * 64;
    if constexpr (PHASE == 1){
        stage_A_gather<K>(ptsT, q, P.gidx, m0, t, As);
        short8v wf[2][O1/64];
        load_W_frags<64,O1>(P.W1, wf, l, w, 0);
        __syncthreads();
        f32x4 acc[4][O1/64] = {};
        mfma_gemm_v2<64,O1>(As, wf, acc, l);
        bias_mfma<O1>(acc, P.b1, l, w, 0);
        zstore_mfma<O1,O1>(acc, P.zbuf, m0, l, w, 0);
        stats_mfma<O1,O1,K,false>(acc, l, w, m0, blk, 0, P.pS,P.pQ,P.gmax,P.gmin);
    } else if constexpr (PHASE == 2){
        stage_A_z<O1>(P.zbuf, m0, P.sc1, P.sh1, t, As);
        short8v wf[O1/32][O2/64];
        load_W_frags<O1,O2>(P.W2, wf, l, w, 0);
        __syncthreads();
        f32x4 acc[4][O2/64] = {};
        mfma_gemm_v2<O1,O2>(As, wf, acc, l);
        bias_mfma<O2>(acc, P.b2, l, w, 0);
        zstore_mfma<O2,O2>(acc, P.zbuf, m0, l, w, 0);
        stats_mfma<O2,O2,K,false>(acc, l, w, m0, blk, 0, P.pS,P.pQ,P.gmax,P.gmin);
    } else {
        stage_A_z<O2>(P.zbuf, m0, P.sc2, P.sh2, t, As);
        __syncthreads();
        constexpr int HH = O3/OH3;
#pragma unroll
        for (int h=0; h<HH; ++h){
            short8v wf[O2/32][OH3/64];
            load_W_frags<O2,OH3>(P.W3, wf, l, w, h*OH3);
            f32x4 acc[4][OH3/64] = {};
            mfma_gemm_v2<O2,OH3>(As, wf, acc, l);
            bias_mfma<OH3>(acc, P.b3, l, w, h*OH3);
            stats_mfma<OH3,O3,K,true>(acc, l, w, m0, blk, h*OH3, P.pS,P.pQ,P.gmax,P.gmin);
        }
    }
}

// grid = 8192 (br2, heaviest first) + 4096 (br1) + 2048 (br0) = 14336
template<int PHASE>
__global__ __launch_bounds__(256) void mlp_stage_kernel(const float* __restrict__ ptsT,
                                                        const float* __restrict__ q,
                                                        BrP p0, BrP p1, BrP p2){
    constexpr int AMX = (PHASE==1) ? 64 : 128;
    __shared__ __align__(16) char As[64*AMX*2];
    int t = threadIdx.x;
    int bx = blockIdx.x;
    if (bx < 8192)        mlp_phase<PHASE,64,128,128,256>(ptsT, q, p2, bx, t, As);
    else if (bx < 12288)  mlp_phase<PHASE,32,128,128,256>(ptsT, q, p1, bx-8192, t, As);
    else                  mlp_phase<PHASE,16, 64, 64,128>(ptsT, q, p0, bx-12288, t, As);
}

struct FinP { const float *pS, *pQ, *g, *bt; float *sc, *sh; int O, nb; double invM; };

__global__ __launch_bounds__(256) void finalize_merged_kernel(FinP f0, FinP f1, FinP f2){
    __shared__ double red[512];
    int bx = blockIdx.x;
    FinP f; int c;
    if (bx < f2.O){ f = f2; c = bx; }
    else if (bx < f2.O + f1.O){ f = f1; c = bx - f2.O; }
    else { f = f0; c = bx - f2.O - f1.O; }
    int t = threadIdx.x;
    double S=0.0, Q=0.0;
    for (int v=t; v<f.nb; v+=256){ S += (double)f.pS[(size_t)v*f.O + c]; Q += (double)f.pQ[(size_t)v*f.O + c]; }
    red[t]=S; red[256+t]=Q;
    __syncthreads();
    for (int s=128; s>0; s>>=1){
        if (t<s){ red[t]+=red[t+s]; red[256+t]+=red[256+t+s]; }
        __syncthreads();
    }
    if (t==0){
        double mean = red[0]*f.invM;
        double var  = red[256]*f.invM - mean*mean;
        double scale = (double)f.g[c] / sqrt(var + 1e-5);
        f.sc[c] = (float)scale;
        f.sh[c] = (float)((double)f.bt[c] - mean*scale);
    }
}

struct OutP { const float *gmax, *gmin, *sc, *sh; int O, logO, chbase; };

__global__ void final_out_merged_kernel(OutP o0, OutP o1, OutP o2, float* __restrict__ outp){
    int bx = blockIdx.x;
    OutP o; int base;
    if (bx < 8192){ o = o2; base = bx; }
    else if (bx < 16384){ o = o1; base = bx - 8192; }
    else { o = o0; base = bx - 16384; }
    int gid = base*256 + threadIdx.x;
    int c  = gid & (o.O-1);
    int bs = gid >> o.logO;
    int b = bs >> 10, s = bs & 1023;
    float scale = o.sc[c];
    float v = (scale >= 0.f) ? o.gmax[gid] : o.gmin[gid];
    float r = fmaxf(0.f, scale*v + o.sh[c]);
    outp[((size_t)(b*640 + o.chbase + c))*SS + s] = r;
}

// =================== SEQUENTIAL fallback path (R8-proven) ===================
template<int PHASE, int K, int O1, int O2, int O3>
__global__ __launch_bounds__(256) void fused_mlp(
    const float* __restrict__ ptsT, const float* __restrict__ q, const int* __restrict__ gidx,
    const u16* __restrict__ Wb1, const float* __restrict__ b1,
    const u16* __restrict__ Wb2, const float* __restrict__ b2,
    const u16* __restrict__ Wb3, const float* __restrict__ b3,
    const float* __restrict__ sc1, const float* __restrict__ sh1,
    const float* __restrict__ sc2, const float* __restrict__ sh2,
    float* __restrict__ pS, float* __restrict__ pQ,
    float* __restrict__ gmax, float* __restrict__ gmin,
    u16* __restrict__ zbuf)
{
    constexpr int OH3 = (O3 > 128) ? 128 : O3;
    constexpr int AMX = (PHASE==1) ? 64 : (PHASE==2 ? O1 : (PHASE==3 ? cmax2(O1,O2) : O2));
    __shared__ __align__(16) char As[64*AMX*2];
    int t = threadIdx.x, l = t & 63, w = t >> 6;
    int m0 = blockIdx.x * 64;

    if constexpr (PHASE == 1){
        stage_A_gather<K>(ptsT, q, gidx, m0, t, As);
        short8v wf[2][O1/64];
        load_W_frags<64,O1>(Wb1, wf, l, w, 0);
        __syncthreads();
        f32x4 acc[4][O1/64] = {};
        mfma_gemm_v2<64,O1>(As, wf, acc, l);
        bias_mfma<O1>(acc, b1, l, w, 0);
        if (zbuf) zstore_mfma<O1,O1>(acc, zbuf, m0, l, w, 0);
        stats_mfma<O1,O1,K,false>(acc, l, w, m0, blockIdx.x, 0, pS,pQ,gmax,gmin);
        return;
    }

    if constexpr (PHASE == 2){
        if (zbuf){
            stage_A_z<O1>(zbuf, m0, sc1, sh1, t, As);
        } else {
            stage_A_gather<K>(ptsT, q, gidx, m0, t, As);
            short8v wf1[2][O1/64];
            load_W_frags<64,O1>(Wb1, wf1, l, w, 0);
            __syncthreads();
            f32x4 acc1[4][O1/64] = {};
            mfma_gemm_v2<64,O1>(As, wf1, acc1, l);
            __syncthreads();
            act_to_As_mfma<O1>(acc1, b1, sc1, sh1, l, w, As);
        }
        short8v wf[O1/32][O2/64];
        load_W_frags<O1,O2>(Wb2, wf, l, w, 0);
        __syncthreads();
        f32x4 acc[4][O2/64] = {};
        mfma_gemm_v2<O1,O2>(As, wf, acc, l);
        bias_mfma<O2>(acc, b2, l, w, 0);
        if (zbuf) zstore_mfma<O2,O2>(acc, zbuf, m0, l, w, 0);
        stats_mfma<O2,O2,K,false>(acc, l, w, m0, blockIdx.x, 0, pS,pQ,gmax,gmin);
        return;
    }

    if constexpr (PHASE == 3){
        stage_A_gather<K>(ptsT, q, gidx, m0, t, As);
        short8v wf1[2][O1/64];
        load_W_frags<64,O1>(Wb1, wf1, l, w, 0);
        __syncthreads();
        f32x4 acc1[4][O1/64] = {};
        mfma_gemm_v2<64,O1>(As, wf1, acc1, l);
        __syncthreads();
        act_to_As_mfma<O1>(acc1, b1, sc1, sh1, l, w, As);
        __syncthreads();
        short8v wf2[O1/32][O2/64];
        load_W_frags<O1,O2>(Wb2, wf2, l, w, 0);
        f32x4 acc2[4][O2/64] = {};
        mfma_gemm_v2<O1,O2>(As, wf2, acc2, l);
        __syncthreads();
        act_to_As_mfma<O2>(acc2, b2, sc2, sh2, l, w, As);
    } else {
        stage_A_z<O2>(zbuf, m0, sc2, sh2, t, As);
    }

    __syncthreads();
    constexpr int HH = O3/OH3;
#pragma unroll
    for (int h=0; h<HH; ++h){
        short8v wf[O2/32][OH3/64];
        load_W_frags<O2,OH3>(Wb3, wf, l, w, h*OH3);
        f32x4 acc[4][OH3/64] = {};
        mfma_gemm_v2<O2,OH3>(As, wf, acc, l);
        bias_mfma<OH3>(acc, b3, l, w, h*OH3);
        stats_mfma<OH3,O3,K,true>(acc, l, w, m0, blockIdx.x, h*OH3, pS,pQ,gmax,gmin);
    }
}

__global__ __launch_bounds__(256) void finalize_d_kernel(const float* __restrict__ pS, const float* __restrict__ pQ,
                                      const float* __restrict__ g, const float* __restrict__ bt,
                                      float* __restrict__ sc, float* __restrict__ sh, int nb, double invM){
    __shared__ double red[512];
    int c = blockIdx.x;
    int O = gridDim.x;
    int t = threadIdx.x;
    double S=0.0, Q=0.0;
    for (int v=t; v<nb; v+=256){ S += (double)pS[(size_t)v*O + c]; Q += (double)pQ[(size_t)v*O + c]; }
    red[t]=S; red[256+t]=Q;
    __syncthreads();
    for (int s=128; s>0; s>>=1){
        if (t<s){ red[t]+=red[t+s]; red[256+t]+=red[256+t+s]; }
        __syncthreads();
    }
    if (t==0){
        double mean = red[0]*invM;
        double var  = red[256]*invM - mean*mean;
        double scale = (double)g[c] / sqrt(var + 1e-5);
        sc[c] = (float)scale;
        sh[c] = (float)((double)bt[c] - mean*scale);
    }
}

__global__ void final_out_kernel(const float* __restrict__ gmax, const float* __restrict__ gmin,
                                 const float* __restrict__ sc, const float* __restrict__ sh,
                                 float* __restrict__ outp, int O, int logO, int chbase){
    int gid = blockIdx.x*256 + threadIdx.x;
    int c  = gid & (O-1);
    int bs = gid >> logO;
    int b = bs >> 10, s = bs & 1023;
    float scale = sc[c];
    float v = (scale >= 0.f) ? gmax[gid] : gmin[gid];
    float r = fmaxf(0.f, scale*v + sh[c]);
    outp[((size_t)(b*640 + chbase + c))*SS + s] = r;
}

__global__ void ws_marker_kernel(float* outp, float wsval){ if (threadIdx.x==0) outp[0] = wsval; }

template<int K, int O1, int O2, int O3>
static void run_branch(const float* ptsT, const float* q, const int* gidx,
                       float* pS, float* pQ, float* gmax, float* gmin,
                       float* sc1, float* sh1, float* sc2, float* sh2, float* sc3, float* sh3,
                       u16* z2buf, bool use_z, const u16* wb,
                       void* const* d_in, int wbase, float* np_out, int chbase, hipStream_t stream)
{
    const int M = BB*SS*K;
    const int nb = M/64;
    auto wp = [&](int jl, int which)->const float* { return (const float*)d_in[2 + (wbase+jl)*4 + which]; };
    const double invM = 1.0 / (double)M;
    u16* zb = use_z ? z2buf : (u16*)nullptr;
    const u16* Wb1 = wb;
    const u16* Wb2 = wb + (size_t)O1*64;
    const u16* Wb3 = wb + (size_t)O1*64 + (size_t)O2*O1;

    fused_mlp<1,K,O1,O2,O3><<<nb,256,0,stream>>>(ptsT,q,gidx,
        Wb1,wp(0,1), Wb2,wp(1,1), Wb3,wp(2,1),
        sc1,sh1, sc2,sh2, pS,pQ, gmax,gmin, zb);
    finalize_d_kernel<<<O1,256,0,stream>>>(pS,pQ, wp(0,2), wp(0,3), sc1, sh1, nb, invM);

    fused_mlp<2,K,O1,O2,O3><<<nb,256,0,stream>>>(ptsT,q,gidx,
        Wb1,wp(0,1), Wb2,wp(1,1), Wb3,wp(2,1),
        sc1,sh1, sc2,sh2, pS,pQ, gmax,gmin, zb);
    finalize_d_kernel<<<O2,256,0,stream>>>(pS,pQ, wp(1,2), wp(1,3), sc2, sh2, nb, invM);

    if (use_z){
        fused_mlp<4,K,O1,O2,O3><<<nb,256,0,stream>>>(ptsT,q,gidx,
            Wb1,wp(0,1), Wb2,wp(1,1), Wb3,wp(2,1),
            sc1,sh1, sc2,sh2, pS,pQ, gmax,gmin, z2buf);
    } else {
        fused_mlp<3,K,O1,O2,O3><<<nb,256,0,stream>>>(ptsT,q,gidx,
            Wb1,wp(0,1), Wb2,wp(1,1), Wb3,wp(2,1),
            sc1,sh1, sc2,sh2, pS,pQ, gmax,gmin, nullptr);
    }
    finalize_d_kernel<<<O3,256,0,stream>>>(pS,pQ, wp(2,2), wp(2,3), sc3, sh3, nb, invM);

    final_out_kernel<<<(BB*SS*O3)/256,256,0,stream>>>(gmax,gmin, sc3,sh3, np_out, O3, (O3==256?8:7), chbase);
}

extern "C" void kernel_launch(void* const* d_in, const int* in_sizes, int n_in,
                              void* d_out, int out_size, void* d_ws, size_t ws_size,
                              hipStream_t stream)
{
    const float* xyz = (const float*)d_in[0];
    const float* pts = (const float*)d_in[1];
    float* outp = (float*)d_out;

    char* wsb = (char*)d_ws;
    size_t off = 0;
    auto alloc = [&](size_t bytes) -> void* {
        off = (off + 255) & ~(size_t)255;
        void* p = wsb + off;
        off += bytes;
        return p;
    };
    // ---- common allocations (both paths) ----
    float* q       = (float*)alloc((size_t)BB*SS*3*4);
    int*   idx0    = (int*)  alloc((size_t)BB*SS*16*4);
    int*   idx1    = (int*)  alloc((size_t)BB*SS*32*4);
    int*   idx2    = (int*)  alloc((size_t)BB*SS*64*4);
    float* ptsT    = (float*)alloc((size_t)BB*NN*64*4);
    u16*   wbf0    = (u16*)  alloc((size_t)16384*2);
    u16*   wbf1    = (u16*)  alloc((size_t)57344*2);
    u16*   wbf2    = (u16*)  alloc((size_t)57344*2);
    float* scsh    = (float*)alloc((size_t)3*6*256*4);
    size_t off_common = off;

    if (off > ws_size){
        ws_marker_kernel<<<1,64,0,stream>>>(outp, (float)ws_size);
        return;
    }

    // ---- try merged allocations ----
    float* pS0 = (float*)alloc((size_t)2048*128*4);
    float* pS1 = (float*)alloc((size_t)4096*256*4);
    float* pS2 = (float*)alloc((size_t)8192*256*4);
    float* pQ0 = (float*)alloc((size_t)2048*128*4);
    float* pQ1 = (float*)alloc((size_t)4096*256*4);
    float* pQ2 = (float*)alloc((size_t)8192*256*4);
    float* gx0 = (float*)alloc((size_t)8192*128*4);
    float* gx1 = (float*)alloc((size_t)8192*256*4);
    float* gx2 = (float*)alloc((size_t)8192*256*4);
    float* gn0 = (float*)alloc((size_t)8192*128*4);
    float* gn1 = (float*)alloc((size_t)8192*256*4);
    float* gn2 = (float*)alloc((size_t)8192*256*4);
    u16*   zb0 = (u16*)  alloc((size_t)131072*64*2);
    u16*   zb1 = (u16*)  alloc((size_t)262144*128*2);
    u16*   zb2 = (u16*)  alloc((size_t)524288*128*2);
    bool merged = (off <= ws_size);

    auto wptr = [&](int layer, int which)->const float* { return (const float*)d_in[2 + layer*4 + which]; };

    // FPS + ptsT transpose + W converts in ONE launch (R8-proven)
    pre_kernel<<<8 + 2048 + 3, 1024, 0, stream>>>(
        xyz, pts, ptsT, q, outp,
        wptr(0,0), wptr(1,0), wptr(2,0), wptr(3,0), wptr(4,0), wptr(5,0), wptr(6,0), wptr(7,0), wptr(8,0),
        wbf0, wbf1, wbf2);

    const float r2a = (float)(0.1*0.1);
    const float r2b = (float)(0.2*0.2);
    const float r2c = (float)(0.4*0.4);
    ballquery_kernel<<<2048, 256, 0, stream>>>(xyz, q, idx0, idx1, idx2, r2a, r2b, r2c);

    float* np_out = outp + (size_t)BB*3*SS;

    if (merged){
        auto SC = [&](int br, int slot)->float* { return scsh + ((size_t)br*6 + slot)*256; };
        BrP P[3];
        const u16* wb[3] = { wbf0, wbf1, wbf2 };
        const int O1s[3] = {64,128,128}, O2s[3] = {64,128,128};
        const int* gidxs[3] = { idx0, idx1, idx2 };
        float* pSs[3] = {pS0,pS1,pS2}; float* pQs[3] = {pQ0,pQ1,pQ2};
        float* gxs[3] = {gx0,gx1,gx2}; float* gns[3] = {gn0,gn1,gn2};
        u16* zbs[3] = {zb0,zb1,zb2};
        for (int br=0; br<3; ++br){
            int wbase = br*3;
            P[br].gidx = gidxs[br];
            P[br].W1 = wb[br];
            P[br].W2 = wb[br] + (size_t)O1s[br]*64;
            P[br].W3 = wb[br] + (size_t)O1s[br]*64 + (size_t)O2s[br]*O1s[br];
            P[br].b1 = wptr(wbase+0,1); P[br].b2 = wptr(wbase+1,1); P[br].b3 = wptr(wbase+2,1);
            P[br].sc1 = SC(br,0); P[br].sh1 = SC(br,1);
            P[br].sc2 = SC(br,2); P[br].sh2 = SC(br,3);
            P[br].pS = pSs[br]; P[br].pQ = pQs[br];
            P[br].gmax = gxs[br]; P[br].gmin = gns[br];
            P[br].zbuf = zbs[br];
        }
        const int nbs[3] = {2048, 4096, 8192};
        const double invMs[3] = {1.0/131072.0, 1.0/262144.0, 1.0/524288.0};
        auto mkFin = [&](int br, int layer, int O, float* sc, float* sh)->FinP{
            FinP f; f.pS = pSs[br]; f.pQ = pQs[br];
            f.g = wptr(br*3+layer,2); f.bt = wptr(br*3+layer,3);
            f.sc = sc; f.sh = sh; f.O = O; f.nb = nbs[br]; f.invM = invMs[br];
            return f;
        };

        mlp_stage_kernel<1><<<14336,256,0,stream>>>(ptsT, q, P[0], P[1], P[2]);
        finalize_merged_kernel<<<64+128+128,256,0,stream>>>(
            mkFin(0,0,64,SC(0,0),SC(0,1)), mkFin(1,0,128,SC(1,0),SC(1,1)), mkFin(2,0,128,SC(2,0),SC(2,1)));

        mlp_stage_kernel<2><<<14336,256,0,stream>>>(ptsT, q, P[0], P[1], P[2]);
        finalize_merged_kernel<<<64+128+128,256,0,stream>>>(
            mkFin(0,1,64,SC(0,2),SC(0,3)), mkFin(1,1,128,SC(1,2),SC(1,3)), mkFin(2,1,128,SC(2,2),SC(2,3)));

        mlp_stage_kernel<4><<<14336,256,0,stream>>>(ptsT, q, P[0], P[1], P[2]);
        finalize_merged_kernel<<<128+256+256,256,0,stream>>>(
            mkFin(0,2,128,SC(0,4),SC(0,5)), mkFin(1,2,256,SC(1,4),SC(1,5)), mkFin(2,2,256,SC(2,4),SC(2,5)));

        OutP o0 = { gx0, gn0, SC(0,4), SC(0,5), 128, 7,   0 };
        OutP o1 = { gx1, gn1, SC(1,4), SC(1,5), 256, 8, 128 };
        OutP o2 = { gx2, gn2, SC(2,4), SC(2,5), 256, 8, 384 };
        final_out_merged_kernel<<<8192+8192+4096,256,0,stream>>>(o0, o1, o2, np_out);
    } else {
        // ---- sequential fallback (R8 path) ----
        off = off_common;
        float* pS   = (float*)alloc((size_t)8192*256*4);
        float* pQ   = (float*)alloc((size_t)8192*256*4);
        float* gmax = (float*)alloc((size_t)8192*256*4);
        float* gmin = (float*)alloc((size_t)8192*256*4);
        if (off > ws_size){
            ws_marker_kernel<<<1,64,0,stream>>>(outp, (float)ws_size);
            return;
        }
        u16* z2buf = (u16*)alloc((size_t)BB*SS*64*128*2);
        bool use_z = (off <= ws_size);
        float* sc1 = scsh+0*256; float* sh1 = scsh+1*256;
        float* sc2 = scsh+2*256; float* sh2 = scsh+3*256;
        float* sc3 = scsh+4*256; float* sh3 = scsh+5*256;

        run_branch<16, 64, 64,128>(ptsT, q, idx0, pS,pQ, gmax,gmin, sc1,sh1,sc2,sh2,sc3,sh3, z2buf, use_z, wbf0, d_in, 0, np_out,   0, stream);
        run_branch<32,128,128,256>(ptsT, q, idx1, pS,pQ, gmax,gmin, sc1,sh1,sc2,sh2,sc3,sh3, z2buf, use_z, wbf1, d_in, 3, np_out, 128, stream);
        run_branch<64,128,128,256>(ptsT, q, idx2, pS,pQ, gmax,gmin, sc1,sh1,sc2,sh2,sc3,sh3, z2buf, use_z, wbf2, d_in, 6, np_out, 384, stream);
    }

    hipError_t e = hipGetLastError();
    if (e != hipSuccess){
        ws_marker_kernel<<<1,64,0,stream>>>(outp, 1000.0f + (float)(int)e);
    }
}

// Round 11
// 2749.049 us; speedup vs baseline: 1.0822x; 1.0822x over previous
//
#include <hip/hip_runtime.h>
#include <stdint.h>

#define BB 8
#define NN 16384
#define SS 1024

typedef unsigned short u16;
typedef float f32x4 __attribute__((ext_vector_type(4)));
typedef short short8v __attribute__((ext_vector_type(8)));
typedef unsigned short us4 __attribute__((ext_vector_type(4)));
typedef unsigned short us8 __attribute__((ext_vector_type(8)));

static __device__ __forceinline__ float bf2f(u16 u){
    union { uint32_t u; float f; } v; v.u = ((uint32_t)u) << 16; return v.f;
}
static __device__ __forceinline__ u16 f2bf(float f){
    union { float f; uint32_t u; } v; v.f = f;
    return (u16)((v.u + 0x7FFFu + ((v.u >> 16) & 1u)) >> 16);
}
static constexpr int cmax2(int a, int b){ return a > b ? a : b; }

// ======== FAT pre-kernel: FPS (blocks 0..7) + ptsT transpose (8..2055) + W convert ====
// FPS floor ~1770us, probed 6 ways (all lose):
//  R1 cross-block agent-atomic exchange: +3us/iter poll on serial path
//  R5 v_pk f32x2: cut issue, flat duration (not issue-bound at margin)
//  R6 waves_per_eu / R7 in-loop "+v" asm: VGPR pinned at 52 -> gfx950 unified-RF
//     allocator parks long-lived arrays in AGPRs; attrs/asm change budget/copies,
//     never placement (R7: per-iter copies, +118us)
//  R10 LDS re-read of coords: ds_read_b32 costs ~5.8cy/WAVE-INSTRUCTION (not bytes);
//     36 reads x 16 waves = ~3340cy/iter LDS issue > ~1650cy AGPR tax -> +210us
// This is R8's measured-best form (2755us total). asm redefinition is LOAD-BEARING
// (pre-loop ONLY): prevents rematerialization of the coord loads.
#define LP 12288
#define SM_FPS (LP*3*4 + SS*4 + 8)

__global__ __launch_bounds__(1024) void pre_kernel(
        const float* __restrict__ xyz, const float* __restrict__ pts,
        float* __restrict__ ptsT, float* __restrict__ q, float* __restrict__ out_xyz,
        const float* __restrict__ w0, const float* __restrict__ w1, const float* __restrict__ w2,
        const float* __restrict__ w3, const float* __restrict__ w4, const float* __restrict__ w5,
        const float* __restrict__ w6, const float* __restrict__ w7, const float* __restrict__ w8,
        u16* __restrict__ wbf0, u16* __restrict__ wbf1, u16* __restrict__ wbf2){
#pragma clang fp contract(off)
    __shared__ __align__(16) char smem_raw[SM_FPS];
    int t = threadIdx.x;

    if (blockIdx.x >= 8){
        int bx = blockIdx.x - 8;
        if (bx < 2048){
            // ---- ptsT transpose branch (64x64 tile, 1024 thr) ----
            float (*tile)[65] = (float (*)[65])smem_raw;
            int b = bx >> 8;
            int n0 = (bx & 255) * 64;
            int ln = t & 63, cr = t >> 6;
            for (int c = cr; c < 64; c += 16){
                float v;
                if (c < 3) v = xyz[((size_t)b*3 + c)*NN + n0 + ln];
                else       v = pts[((size_t)b*61 + (c-3))*NN + n0 + ln];
                tile[ln][c] = v;
            }
            __syncthreads();
            int lc = t & 63, nr = t >> 6;
            for (int n = nr; n < 64; n += 16){
                ptsT[((size_t)b*NN + n0 + n)*64 + lc] = tile[n][lc];
            }
        } else {
            // ---- weight fp32->bf16 convert branch (one block per MLP branch) ----
            int br = bx - 2048;
            const float* A; const float* B; const float* C; u16* out; int na, nb2, nc;
            if (br == 0){ A=w0; na=4096;  B=w1; nb2=4096;  C=w2; nc=8192;  out=wbf0; }
            else if (br == 1){ A=w3; na=8192; B=w4; nb2=16384; C=w5; nc=32768; out=wbf1; }
            else { A=w6; na=8192; B=w7; nb2=16384; C=w8; nc=32768; out=wbf2; }
            int tot = na + nb2 + nc;
            for (int i = t; i < tot; i += 1024){
                float v;
                if (i < na) v = A[i];
                else if (i < na+nb2) v = B[i-na];
                else v = C[i-na-nb2];
                out[i] = f2bf(v);
            }
        }
        return;
    }

    // ---- FPS branch ----
    float* lx = (float*)smem_raw;
    float* ly = lx + LP;
    float* lz = ly + LP;
    int*  hist = (int*)(lz + LP);
    unsigned long long* slotp = (unsigned long long*)(hist + SS);
    int b = blockIdx.x;
    const float* xb = xyz + (size_t)b*3*NN;
    float px[16], py[16], pz[16], dd[16];
#pragma unroll
    for (int j=0;j<16;++j){
        int n = t + j*1024;
        px[j] = xb[n];
        py[j] = xb[NN+n];
        pz[j] = xb[2*NN+n];
        dd[j] = 1e10f;
    }
    // opaque redefinition: compiler cannot rematerialize the loads (pre-loop ONLY —
    // in-loop form forces per-iter AGPR<->VGPR copies, R7: +118us)
#pragma unroll
    for (int j=0;j<16;++j){
        asm volatile("" : "+v"(px[j]), "+v"(py[j]), "+v"(pz[j]));
    }
    for (int idx = t; idx < LP; idx += 1024){
        lx[idx] = xb[idx];
        ly[idx] = xb[NN+idx];
        lz[idx] = xb[2*NN+idx];
    }
    if (t == 0) *slotp = 0ull;
    __syncthreads();

    int lane = t & 63;
    int far = 0;
    float cx = xb[0], cy = xb[NN], cz = xb[2*NN];
    for (int it=0; it<SS; ++it){
        if (t==0) hist[it] = far;
#pragma unroll
        for (int j=0;j<16;++j){
            float dx = px[j]-cx, dy = py[j]-cy, dz = pz[j]-cz;
            float d = dx*dx + dy*dy;
            d = d + dz*dz;
            dd[j] = fminf(dd[j], d);   // np.minimum, exact
        }
        // per-thread max tree (compiler fuses to v_max3)
        float m01 = fmaxf(dd[0], dd[1]),  m23 = fmaxf(dd[2], dd[3]);
        float m45 = fmaxf(dd[4], dd[5]),  m67 = fmaxf(dd[6], dd[7]);
        float m89 = fmaxf(dd[8], dd[9]),  mab = fmaxf(dd[10], dd[11]);
        float mcd = fmaxf(dd[12], dd[13]), mef = fmaxf(dd[14], dd[15]);
        float ma = fmaxf(fmaxf(m01, m23), fmaxf(m45, m67));
        float mb = fmaxf(fmaxf(m89, mab), fmaxf(mcd, mef));
        float mx = fmaxf(ma, mb);
        // first j with dd[j]==mx (descending overwrite -> smallest j -> smallest n)
        int bj = 0;
#pragma unroll
        for (int j=15; j>=0; --j){
            if (dd[j] == mx) bj = j;
        }
        int bn = t + (bj << 10);
        // pack: [it+1:14][f32bits:32][16383-n:14]; u64 max == (value, lowest-n) argmax
        unsigned long long pk = ((unsigned long long)(unsigned)(it+1) << 46)
                              | ((unsigned long long)__float_as_uint(mx) << 14)
                              | (unsigned long long)(unsigned)(16383 - bn);
#pragma unroll
        for (int off=32; off>0; off>>=1){
            unsigned long long o = __shfl_down(pk, off);
            pk = (o > pk) ? o : pk;
        }
        if (lane == 0) atomicMax(slotp, pk);
        __syncthreads();
        unsigned long long win = *slotp;
        far = 16383 - (int)(win & 0x3FFFull);
        if (far < LP){
            cx = lx[far]; cy = ly[far]; cz = lz[far];
        } else {
            cx = xb[far]; cy = xb[NN+far]; cz = xb[2*NN+far];
        }
    }
    // epilogue: fold gather_q — write q + new_xyz output directly from history
    __syncthreads();
    {
        int s = t;
        int fidx = hist[s];
        float vx, vy, vz;
        if (fidx < LP){ vx = lx[fidx]; vy = ly[fidx]; vz = lz[fidx]; }
        else { vx = xb[fidx]; vy = xb[NN+fidx]; vz = xb[2*NN+fidx]; }
        int gi = b*SS + s;
        q[gi*3+0] = vx; q[gi*3+1] = vy; q[gi*3+2] = vz;
        out_xyz[((size_t)b*3+0)*SS + s] = vx;
        out_xyz[((size_t)b*3+1)*SS + s] = vy;
        out_xyz[((size_t)b*3+2)*SS + s] = vz;
    }
}

// ---------------- ball query ----------------
__global__ __launch_bounds__(256) void ballquery_kernel(const float* __restrict__ xyz, const float* __restrict__ q,
        int* __restrict__ idx0, int* __restrict__ idx1, int* __restrict__ idx2,
        float r2a, float r2b, float r2c){
#pragma clang fp contract(off)
    __shared__ int lds[4][112];
    int t = threadIdx.x;
    int w = t >> 6, lane = t & 63;
    int qi = blockIdx.x*4 + w;
    int b = qi >> 10;
    const float* xb = xyz + (size_t)b*3*NN;
    float qx = q[qi*3], qy = q[qi*3+1], qz = q[qi*3+2];
    float qn = qx*qx + qy*qy; qn = qn + qz*qz;
    int* l0 = lds[w];
    int* l1 = l0 + 16;
    int* l2 = l0 + 48;
    l0[lane] = 0;
    if (lane < 48) l0[64+lane] = 0;
    int c0=0, c1=0, c2=0;
    uint64_t below = (1ull << lane) - 1ull;
    for (int ch=0; ch<256; ++ch){
        int n = ch*64 + lane;
        float x = xb[n], y = xb[NN+n], z = xb[2*NN+n];
        float dn = x*x + y*y; dn = dn + z*z;
        float dot = qx*x + qy*y; dot = dot + qz*z;
        float d = -2.0f*dot + qn;
        d = d + dn;
        bool o0 = d <= r2a, o1 = d <= r2b, o2 = d <= r2c;
        uint64_t m0 = __ballot(o0), m1 = __ballot(o1), m2 = __ballot(o2);
        if (c0 < 16){
            int p = c0 + (int)__popcll(m0 & below);
            if (o0 && p < 16) l0[p] = n;
            c0 += (int)__popcll(m0); if (c0 > 16) c0 = 16;
        }
        if (c1 < 32){
            int p = c1 + (int)__popcll(m1 & below);
            if (o1 && p < 32) l1[p] = n;
            c1 += (int)__popcll(m1); if (c1 > 32) c1 = 32;
        }
        if (c2 < 64){
            int p = c2 + (int)__popcll(m2 & below);
            if (o2 && p < 64) l2[p] = n;
            c2 += (int)__popcll(m2); if (c2 > 64) c2 = 64;
        }
        if (c0>=16 && c1>=32 && c2>=64) break;
    }
    __syncthreads();
    int f0 = l0[0], f1 = l1[0], f2 = l2[0];
    if (lane >= c0 && lane < 16) l0[lane] = f0;
    if (lane >= c1 && lane < 32) l1[lane] = f1;
    if (lane >= c2)              l2[lane] = f2;
    __syncthreads();
    if (lane < 16) idx0[(size_t)qi*16 + lane] = l0[lane];
    if (lane < 32) idx1[(size_t)qi*32 + lane] = l1[lane];
    idx2[(size_t)qi*64 + lane] = l2[lane];
}

// =================== MFMA fused MLP (W in registers) ===================
//  As (LDS): [64 rows][CC] bf16, byte = row*CC*2 + (kbyte ^ ((row&7)<<4))  (T2 swizzle)
//  W: bf16 in global (converted once); each wave loads its fragments into VGPRs
//  (L2-broadcast across blocks). A/B frags: identical per-lane k-order
//  (k = ks*32 + (l>>4)*8 + 0..7); MFMA k-indexing is operand-symmetric.
//  C/D (HW-verified): col=lane&15, row=(lane>>4)*4+reg.

template<int CC, int OH>
__device__ __forceinline__ void load_W_frags(const u16* __restrict__ Wb,
                                             short8v (&wf)[CC/32][OH/64],
                                             int l, int w, int hoff){
    int rl = l & 15, kg = l >> 4;
#pragma unroll
    for (int ks=0; ks<CC/32; ++ks)
#pragma unroll
    for (int tc=0; tc<OH/64; ++tc){
        int col = hoff + w*(OH/4) + tc*16 + rl;
        wf[ks][tc] = *(const short8v*)(Wb + (size_t)col*CC + ks*32 + kg*8);
    }
}

template<int K>
__device__ __forceinline__ void stage_A_gather(const float* __restrict__ ptsT, const float* __restrict__ q,
                                               const int* __restrict__ gidx, int m0, int t, char* __restrict__ As){
    int r = t >> 2, q4 = t & 3;
    int m = m0 + r;
    int idx = gidx[m];
    int bs = m / K;
    int b = bs >> 10;
    const float* base = ptsT + ((size_t)b*NN + idx)*64;
    float qx=0.f, qy=0.f, qz=0.f;
    if (q4 == 0){ qx = q[bs*3]; qy = q[bs*3+1]; qz = q[bs*3+2]; }
    int rx = (r & 7) << 4;
#pragma unroll
    for (int ii=0; ii<4; ++ii){
        int c0 = q4*16 + ii*4;
        float4 v = *(const float4*)(base + c0);
        if (q4==0 && ii==0){ v.x -= qx; v.y -= qy; v.z -= qz; }
        us4 u;
        u[0]=f2bf(v.x); u[1]=f2bf(v.y); u[2]=f2bf(v.z); u[3]=f2bf(v.w);
        *(us4*)(As + r*128 + ((c0*2) ^ rx)) = u;
    }
}

template<int OP>
__device__ __forceinline__ void stage_A_z(const u16* __restrict__ zbuf, int m0,
                                          const float* __restrict__ sc, const float* __restrict__ sh,
                                          int t, char* __restrict__ As){
    constexpr int CQ = OP/4;
    for (int s = t; s < 64*CQ; s += 256){
        int r = s / CQ, cq = s - r*CQ;
        us4 zv = *(const us4*)&zbuf[((size_t)(m0+r))*OP + cq*4];
        int c = cq*4;
        us4 u;
        u[0] = f2bf(fmaxf(0.f, bf2f(zv[0])*sc[c+0] + sh[c+0]));
        u[1] = f2bf(fmaxf(0.f, bf2f(zv[1])*sc[c+1] + sh[c+1]));
        u[2] = f2bf(fmaxf(0.f, bf2f(zv[2])*sc[c+2] + sh[c+2]));
        u[3] = f2bf(fmaxf(0.f, bf2f(zv[3])*sc[c+3] + sh[c+3]));
        *(us4*)(As + r*(OP*2) + ((cq*8) ^ ((r&7)<<4))) = u;
    }
}

template<int CC, int OH>
__device__ __forceinline__ void mfma_gemm_v2(const char* __restrict__ As,
                                             const short8v (&wf)[CC/32][OH/64],
                                             f32x4 (&acc)[4][OH/64], int l){
    constexpr int CCB = CC*2;
    int rl = l & 15, kg = l >> 4;
    const char* ap = As + rl*CCB;
    int axor = (rl & 7) << 4;
#pragma unroll
    for (int ks=0; ks<CC/32; ++ks){
        int karg = ((ks<<6) | (kg<<4)) ^ axor;
        short8v a0 = *(const short8v*)(ap + 0*16*CCB + karg);
        short8v a1 = *(const short8v*)(ap + 1*16*CCB + karg);
        short8v a2 = *(const short8v*)(ap + 2*16*CCB + karg);
        short8v a3 = *(const short8v*)(ap + 3*16*CCB + karg);
#pragma unroll
        for (int tc=0; tc<OH/64; ++tc){
            acc[0][tc] = __builtin_amdgcn_mfma_f32_16x16x32_bf16(a0, wf[ks][tc], acc[0][tc], 0,0,0);
            acc[1][tc] = __builtin_amdgcn_mfma_f32_16x16x32_bf16(a1, wf[ks][tc], acc[1][tc], 0,0,0);
            acc[2][tc] = __builtin_amdgcn_mfma_f32_16x16x32_bf16(a2, wf[ks][tc], acc[2][tc], 0,0,0);
            acc[3][tc] = __builtin_amdgcn_mfma_f32_16x16x32_bf16(a3, wf[ks][tc], acc[3][tc], 0,0,0);
        }
    }
}

template<int OH>
__device__ __forceinline__ void bias_mfma(f32x4 (&acc)[4][OH/64], const float* __restrict__ bsrc,
                                          int l, int w, int coff){
#pragma unroll
    for (int tc=0; tc<OH/64; ++tc){
        float bb = bsrc[coff + w*(OH/4) + tc*16 + (l&15)];
#pragma unroll
        for (int tr=0; tr<4; ++tr)
#pragma unroll
        for (int e=0; e<4; ++e) acc[tr][tc][e] += bb;
    }
}

template<int OH, int OT>
__device__ __forceinline__ void zstore_mfma(f32x4 (&acc)[4][OH/64], u16* __restrict__ zbuf,
                                            int m0, int l, int w, int coff){
#pragma unroll
    for (int tr=0; tr<4; ++tr)
#pragma unroll
    for (int e=0; e<4; ++e){
        int row = tr*16 + (l>>4)*4 + e;
#pragma unroll
        for (int tc=0; tc<OH/64; ++tc){
            int c = coff + w*(OH/4) + tc*16 + (l&15);
            zbuf[((size_t)(m0+row))*OT + c] = f2bf(acc[tr][tc][e]);
        }
    }
}

// per-col sums over all 64 rows live in ONE wave -> in-lane + shfl_xor(16/32), no LDS.
template<int OH, int OT, int K, bool EXT>
__device__ __forceinline__ void stats_mfma(f32x4 (&acc)[4][OH/64], int l, int w, int m0, int blk, int coff,
    float* __restrict__ pS, float* __restrict__ pQ,
    float* __restrict__ gmax, float* __restrict__ gmin){
#pragma unroll
    for (int tc=0; tc<OH/64; ++tc){
        float s1 = 0.f, s2 = 0.f;
        float mxr[4], mnr[4];
#pragma unroll
        for (int tr=0; tr<4; ++tr){
            float v0=acc[tr][tc][0], v1=acc[tr][tc][1], v2=acc[tr][tc][2], v3=acc[tr][tc][3];
            s1 += (v0+v1)+(v2+v3);
            s2 += (v0*v0+v1*v1)+(v2*v2+v3*v3);
            if (EXT){
                mxr[tr] = fmaxf(fmaxf(v0,v1),fmaxf(v2,v3));
                mnr[tr] = fminf(fminf(v0,v1),fminf(v2,v3));
            }
        }
        s1 += __shfl_xor(s1,16); s1 += __shfl_xor(s1,32);
        s2 += __shfl_xor(s2,16); s2 += __shfl_xor(s2,32);
        if (EXT){
#pragma unroll
            for (int tr=0; tr<4; ++tr){
                mxr[tr] = fmaxf(mxr[tr], __shfl_xor(mxr[tr],16));
                mxr[tr] = fmaxf(mxr[tr], __shfl_xor(mxr[tr],32));
                mnr[tr] = fminf(mnr[tr], __shfl_xor(mnr[tr],16));
                mnr[tr] = fminf(mnr[tr], __shfl_xor(mnr[tr],32));
            }
        }
        if (l < 16){
            int c = coff + w*(OH/4) + tc*16 + l;
            pS[(size_t)blk*OT + c] = s1;
            pQ[(size_t)blk*OT + c] = s2;
            if (EXT){
                constexpr int G = 64/K, WG = K/16;
#pragma unroll
                for (int g=0; g<G; ++g){
                    float M1 = mxr[g*WG], M2 = mnr[g*WG];
#pragma unroll
                    for (int ww=1; ww<WG; ++ww){
                        M1 = fmaxf(M1, mxr[g*WG+ww]);
                        M2 = fminf(M2, mnr[g*WG+ww]);
                    }
                    gmax[(size_t)(m0/K + g)*OT + c] = M1;
                    gmin[(size_t)(m0/K + g)*OT + c] = M2;
                }
            }
        }
    }
}

// fallback path (no zbuf): acc -> BN+relu -> As bf16 (swizzled), scattered u16 ds writes
template<int OH>
__device__ __forceinline__ void act_to_As_mfma(f32x4 (&acc)[4][OH/64], const float* __restrict__ bsrc,
    const float* __restrict__ sc, const float* __restrict__ sh, int l, int w, char* __restrict__ As){
#pragma unroll
    for (int tc=0; tc<OH/64; ++tc){
        int c = w*(OH/4) + tc*16 + (l&15);
        float bb = bsrc[c], scv = sc[c], shv = sh[c];
#pragma unroll
        for (int tr=0; tr<4; ++tr)
#pragma unroll
        for (int e=0; e<4; ++e){
            int row = tr*16 + (l>>4)*4 + e;
            float vv = fmaxf(0.f, (acc[tr][tc][e]+bb)*scv + shv);
            *(u16*)(As + row*(OH*2) + ((2*c) ^ ((row&7)<<4))) = f2bf(vv);
        }
    }
}

template<int PHASE, int K, int O1, int O2, int O3>
__global__ __launch_bounds__(256) void fused_mlp(
    const float* __restrict__ ptsT, const float* __restrict__ q, const int* __restrict__ gidx,
    const u16* __restrict__ Wb1, const float* __restrict__ b1,
    const u16* __restrict__ Wb2, const float* __restrict__ b2,
    const u16* __restrict__ Wb3, const float* __restrict__ b3,
    const float* __restrict__ sc1, const float* __restrict__ sh1,
    const float* __restrict__ sc2, const float* __restrict__ sh2,
    float* __restrict__ pS, float* __restrict__ pQ,
    float* __restrict__ gmax, float* __restrict__ gmin,
    u16* __restrict__ zbuf)
{
    constexpr int OH3 = (O3 > 128) ? 128 : O3;
    constexpr int AMX = (PHASE==1) ? 64 : (PHASE==2 ? O1 : (PHASE==3 ? cmax2(O1,O2) : O2));
    __shared__ __align__(16) char As[64*AMX*2];
    int t = threadIdx.x, l = t & 63, w = t >> 6;
    int m0 = blockIdx.x * 64;

    if constexpr (PHASE == 1){
        stage_A_gather<K>(ptsT, q, gidx, m0, t, As);
        short8v wf[2][O1/64];
        load_W_frags<64,O1>(Wb1, wf, l, w, 0);
        __syncthreads();
        f32x4 acc[4][O1/64] = {};
        mfma_gemm_v2<64,O1>(As, wf, acc, l);
        bias_mfma<O1>(acc, b1, l, w, 0);
        if (zbuf) zstore_mfma<O1,O1>(acc, zbuf, m0, l, w, 0);
        stats_mfma<O1,O1,K,false>(acc, l, w, m0, blockIdx.x, 0, pS,pQ,gmax,gmin);
        return;
    }

    if constexpr (PHASE == 2){
        if (zbuf){
            stage_A_z<O1>(zbuf, m0, sc1, sh1, t, As);
        } else {
            stage_A_gather<K>(ptsT, q, gidx, m0, t, As);
            short8v wf1[2][O1/64];
            load_W_frags<64,O1>(Wb1, wf1, l, w, 0);
            __syncthreads();
            f32x4 acc1[4][O1/64] = {};
            mfma_gemm_v2<64,O1>(As, wf1, acc1, l);
            __syncthreads();
            act_to_As_mfma<O1>(acc1, b1, sc1, sh1, l, w, As);
        }
        short8v wf[O1/32][O2/64];
        load_W_frags<O1,O2>(Wb2, wf, l, w, 0);
        __syncthreads();
        f32x4 acc[4][O2/64] = {};
        mfma_gemm_v2<O1,O2>(As, wf, acc, l);
        bias_mfma<O2>(acc, b2, l, w, 0);
        if (zbuf) zstore_mfma<O2,O2>(acc, zbuf, m0, l, w, 0);
        stats_mfma<O2,O2,K,false>(acc, l, w, m0, blockIdx.x, 0, pS,pQ,gmax,gmin);
        return;
    }

    if constexpr (PHASE == 3){
        stage_A_gather<K>(ptsT, q, gidx, m0, t, As);
        short8v wf1[2][O1/64];
        load_W_frags<64,O1>(Wb1, wf1, l, w, 0);
        __syncthreads();
        f32x4 acc1[4][O1/64] = {};
        mfma_gemm_v2<64,O1>(As, wf1, acc1, l);
        __syncthreads();
        act_to_As_mfma<O1>(acc1, b1, sc1, sh1, l, w, As);
        __syncthreads();
        short8v wf2[O1/32][O2/64];
        load_W_frags<O1,O2>(Wb2, wf2, l, w, 0);
        f32x4 acc2[4][O2/64] = {};
        mfma_gemm_v2<O1,O2>(As, wf2, acc2, l);
        __syncthreads();
        act_to_As_mfma<O2>(acc2, b2, sc2, sh2, l, w, As);
    } else {
        // PHASE 4
        stage_A_z<O2>(zbuf, m0, sc2, sh2, t, As);
    }

    __syncthreads();
    constexpr int HH = O3/OH3;
#pragma unroll
    for (int h=0; h<HH; ++h){
        short8v wf[O2/32][OH3/64];
        load_W_frags<O2,OH3>(Wb3, wf, l, w, h*OH3);
        f32x4 acc[4][OH3/64] = {};
        mfma_gemm_v2<O2,OH3>(As, wf, acc, l);
        bias_mfma<OH3>(acc, b3, l, w, h*OH3);
        stats_mfma<OH3,O3,K,true>(acc, l, w, m0, blockIdx.x, h*OH3, pS,pQ,gmax,gmin);
        // As is read-only in this loop: no barrier between halves needed
    }
}

// ---------------- finalize BN stats (fp64 accumulation) ----------------
__global__ __launch_bounds__(256) void finalize_d_kernel(const float* __restrict__ pS, const float* __restrict__ pQ,
                                      const float* __restrict__ g, const float* __restrict__ bt,
                                      float* __restrict__ sc, float* __restrict__ sh, int nb, double invM){
    __shared__ double red[512];
    int c = blockIdx.x;
    int O = gridDim.x;
    int t = threadIdx.x;
    double S=0.0, Q=0.0;
    for (int v=t; v<nb; v+=256){ S += (double)pS[(size_t)v*O + c]; Q += (double)pQ[(size_t)v*O + c]; }
    red[t]=S; red[256+t]=Q;
    __syncthreads();
    for (int s=128; s>0; s>>=1){
        if (t<s){ red[t]+=red[t+s]; red[256+t]+=red[256+t+s]; }
        __syncthreads();
    }
    if (t==0){
        double mean = red[0]*invM;
        double var  = red[256]*invM - mean*mean;
        double scale = (double)g[c] / sqrt(var + 1e-5);
        sc[c] = (float)scale;
        sh[c] = (float)((double)bt[c] - mean*scale);
    }
}

// ---------------- BN+relu on pooled extrema -> output (fp32) ----------------
__global__ void final_out_kernel(const float* __restrict__ gmax, const float* __restrict__ gmin,
                                 const float* __restrict__ sc, const float* __restrict__ sh,
                                 float* __restrict__ outp, int O, int logO, int chbase){
    int gid = blockIdx.x*256 + threadIdx.x;
    int c  = gid & (O-1);
    int bs = gid >> logO;
    int b = bs >> 10, s = bs & 1023;
    float scale = sc[c];
    float v = (scale >= 0.f) ? gmax[gid] : gmin[gid];
    float r = fmaxf(0.f, scale*v + sh[c]);
    outp[((size_t)(b*640 + chbase + c))*SS + s] = r;
}

__global__ void ws_marker_kernel(float* outp, float wsval){ if (threadIdx.x==0) outp[0] = wsval; }

template<int K, int O1, int O2, int O3>
static void run_branch(const float* ptsT, const float* q, const int* gidx,
                       float* pS, float* pQ, float* gmax, float* gmin,
                       float* sc1, float* sh1, float* sc2, float* sh2, float* sc3, float* sh3,
                       u16* z2buf, bool use_z, const u16* wb,
                       void* const* d_in, int wbase, float* np_out, int chbase, hipStream_t stream)
{
    const int M = BB*SS*K;
    const int nb = M/64;
    auto wp = [&](int jl, int which)->const float* { return (const float*)d_in[2 + (wbase+jl)*4 + which]; };
    const double invM = 1.0 / (double)M;
    u16* zb = use_z ? z2buf : (u16*)nullptr;
    const u16* Wb1 = wb;
    const u16* Wb2 = wb + (size_t)O1*64;
    const u16* Wb3 = wb + (size_t)O1*64 + (size_t)O2*O1;

    fused_mlp<1,K,O1,O2,O3><<<nb,256,0,stream>>>(ptsT,q,gidx,
        Wb1,wp(0,1), Wb2,wp(1,1), Wb3,wp(2,1),
        sc1,sh1, sc2,sh2, pS,pQ, gmax,gmin, zb);
    finalize_d_kernel<<<O1,256,0,stream>>>(pS,pQ, wp(0,2), wp(0,3), sc1, sh1, nb, invM);

    fused_mlp<2,K,O1,O2,O3><<<nb,256,0,stream>>>(ptsT,q,gidx,
        Wb1,wp(0,1), Wb2,wp(1,1), Wb3,wp(2,1),
        sc1,sh1, sc2,sh2, pS,pQ, gmax,gmin, zb);
    finalize_d_kernel<<<O2,256,0,stream>>>(pS,pQ, wp(1,2), wp(1,3), sc2, sh2, nb, invM);

    if (use_z){
        fused_mlp<4,K,O1,O2,O3><<<nb,256,0,stream>>>(ptsT,q,gidx,
            Wb1,wp(0,1), Wb2,wp(1,1), Wb3,wp(2,1),
            sc1,sh1, sc2,sh2, pS,pQ, gmax,gmin, z2buf);
    } else {
        fused_mlp<3,K,O1,O2,O3><<<nb,256,0,stream>>>(ptsT,q,gidx,
            Wb1,wp(0,1), Wb2,wp(1,1), Wb3,wp(2,1),
            sc1,sh1, sc2,sh2, pS,pQ, gmax,gmin, nullptr);
    }
    finalize_d_kernel<<<O3,256,0,stream>>>(pS,pQ, wp(2,2), wp(2,3), sc3, sh3, nb, invM);

    final_out_kernel<<<(BB*SS*O3)/256,256,0,stream>>>(gmax,gmin, sc3,sh3, np_out, O3, (O3==256?8:7), chbase);
}

extern "C" void kernel_launch(void* const* d_in, const int* in_sizes, int n_in,
                              void* d_out, int out_size, void* d_ws, size_t ws_size,
                              hipStream_t stream)
{
    const float* xyz = (const float*)d_in[0];
    const float* pts = (const float*)d_in[1];
    float* outp = (float*)d_out;

    char* wsb = (char*)d_ws;
    size_t off = 0;
    auto alloc = [&](size_t bytes) -> void* {
        off = (off + 255) & ~(size_t)255;
        void* p = wsb + off;
        off += bytes;
        return p;
    };
    float* q       = (float*)alloc((size_t)BB*SS*3*4);
    int*   idx0    = (int*)  alloc((size_t)BB*SS*16*4);
    int*   idx1    = (int*)  alloc((size_t)BB*SS*32*4);
    int*   idx2    = (int*)  alloc((size_t)BB*SS*64*4);
    float* ptsT    = (float*)alloc((size_t)BB*NN*64*4);
    float* pS      = (float*)alloc((size_t)8192*256*4);
    float* pQ      = (float*)alloc((size_t)8192*256*4);
    float* gmax    = (float*)alloc((size_t)8192*256*4);
    float* gmin    = (float*)alloc((size_t)8192*256*4);
    float* sc1     = (float*)alloc(256*4);
    float* sh1     = (float*)alloc(256*4);
    float* sc2     = (float*)alloc(256*4);
    float* sh2     = (float*)alloc(256*4);
    float* sc3     = (float*)alloc(256*4);
    float* sh3     = (float*)alloc(256*4);
    u16*   wbf0    = (u16*)  alloc((size_t)16384*2);
    u16*   wbf1    = (u16*)  alloc((size_t)57344*2);
    u16*   wbf2    = (u16*)  alloc((size_t)57344*2);

    if (off > ws_size){
        ws_marker_kernel<<<1,64,0,stream>>>(outp, (float)ws_size);
        return;
    }

    u16* z2buf = (u16*)alloc((size_t)BB*SS*64*128*2);
    bool use_z = (off <= ws_size);

    auto wptr = [&](int layer)->const float* { return (const float*)d_in[2 + layer*4 + 0]; };

    // FPS + ptsT transpose + W converts in ONE launch: 8 fps blocks land on 8 CUs,
    // 2048 transpose + 3 convert blocks fill the other 248 CUs under fps's shadow.
    pre_kernel<<<8 + 2048 + 3, 1024, 0, stream>>>(
        xyz, pts, ptsT, q, outp,
        wptr(0), wptr(1), wptr(2), wptr(3), wptr(4), wptr(5), wptr(6), wptr(7), wptr(8),
        wbf0, wbf1, wbf2);

    const float r2a = (float)(0.1*0.1);
    const float r2b = (float)(0.2*0.2);
    const float r2c = (float)(0.4*0.4);
    ballquery_kernel<<<2048, 256, 0, stream>>>(xyz, q, idx0, idx1, idx2, r2a, r2b, r2c);

    float* np_out = outp + (size_t)BB*3*SS;
    run_branch<16, 64, 64,128>(ptsT, q, idx0, pS,pQ, gmax,gmin, sc1,sh1,sc2,sh2,sc3,sh3, z2buf, use_z, wbf0, d_in, 0, np_out,   0, stream);
    run_branch<32,128,128,256>(ptsT, q, idx1, pS,pQ, gmax,gmin, sc1,sh1,sc2,sh2,sc3,sh3, z2buf, use_z, wbf1, d_in, 3, np_out, 128, stream);
    run_branch<64,128,128,256>(ptsT, q, idx2, pS,pQ, gmax,gmin, sc1,sh1,sc2,sh2,sc3,sh3, z2buf, use_z, wbf2, d_in, 6, np_out, 384, stream);

    hipError_t e = hipGetLastError();
    if (e != hipSuccess){
        ws_marker_kernel<<<1,64,0,stream>>>(outp, 1000.0f + (float)(int)e);
    }
}